// Round 1
// baseline (510.730 us; speedup 1.0000x reference)
//
#include <hip/hip_runtime.h>

#define N_NODES 100000
#define N_EDGES 1600000
#define IN_DIM  128
#define HIDDEN  128
#define OUT_DIM 64

#define SCAN_BLOCK 256
#define SCAN_ITEMS 4
#define SCAN_CHUNK (SCAN_BLOCK * SCAN_ITEMS)          // 1024
#define SCAN_NB ((N_NODES + SCAN_CHUNK - 1) / SCAN_CHUNK)  // 98

// ---------------- preprocessing: degree histogram + CSR by dst ----------------

__global__ void k_init(int* __restrict__ cnt) {
    int i = blockIdx.x * 256 + threadIdx.x;
    if (i < N_NODES) cnt[i] = 0;
}

__global__ void k_hist(const int* __restrict__ ei, int* __restrict__ cnt) {
    int e = blockIdx.x * 256 + threadIdx.x;
    if (e < N_EDGES) atomicAdd(&cnt[ei[N_EDGES + e]], 1);
}

__global__ void k_scanA(const int* __restrict__ cnt, int* __restrict__ partials) {
    __shared__ int sd[SCAN_BLOCK];
    int b = blockIdx.x;
    int i0 = b * SCAN_CHUNK + threadIdx.x * SCAN_ITEMS;
    int s = 0;
    #pragma unroll
    for (int j = 0; j < SCAN_ITEMS; j++) {
        int i = i0 + j;
        if (i < N_NODES) s += cnt[i];
    }
    sd[threadIdx.x] = s;
    __syncthreads();
    for (int off = SCAN_BLOCK / 2; off > 0; off >>= 1) {
        if (threadIdx.x < off) sd[threadIdx.x] += sd[threadIdx.x + off];
        __syncthreads();
    }
    if (threadIdx.x == 0) partials[b] = sd[0];
}

__global__ void k_scanB(int* __restrict__ partials, int* __restrict__ offs) {
    if (threadIdx.x == 0 && blockIdx.x == 0) {
        int run = 0;
        for (int b = 0; b < SCAN_NB; b++) {
            int t = partials[b];
            partials[b] = run;     // becomes exclusive block offset
            run += t;
        }
        offs[N_NODES] = run;       // == N_EDGES
    }
}

__global__ void k_scanC(const int* __restrict__ cnt, const int* __restrict__ partials,
                        int* __restrict__ offs, int* __restrict__ cursor,
                        float* __restrict__ dinv) {
    __shared__ int sd[SCAN_BLOCK];
    int b = blockIdx.x;
    int i0 = b * SCAN_CHUNK + threadIdx.x * SCAN_ITEMS;
    int v[SCAN_ITEMS];
    int s = 0;
    #pragma unroll
    for (int j = 0; j < SCAN_ITEMS; j++) {
        int i = i0 + j;
        v[j] = (i < N_NODES) ? cnt[i] : 0;
        s += v[j];
    }
    sd[threadIdx.x] = s;
    __syncthreads();
    // inclusive Hillis-Steele over per-thread sums
    for (int off = 1; off < SCAN_BLOCK; off <<= 1) {
        int t = 0;
        if ((int)threadIdx.x >= off) t = sd[threadIdx.x - off];
        __syncthreads();
        sd[threadIdx.x] += t;
        __syncthreads();
    }
    int run = partials[b] + sd[threadIdx.x] - s;   // block base + exclusive thread prefix
    #pragma unroll
    for (int j = 0; j < SCAN_ITEMS; j++) {
        int i = i0 + j;
        if (i < N_NODES) {
            offs[i]   = run;
            cursor[i] = run;
            dinv[i]   = rsqrtf((float)(v[j] + 1));  // +1: self-loop
            run += v[j];
        }
    }
}

__global__ void k_bucket(const int* __restrict__ ei, int* __restrict__ cursor,
                         int* __restrict__ ssrc) {
    int e = blockIdx.x * 256 + threadIdx.x;
    if (e < N_EDGES) {
        int d = ei[N_EDGES + e];
        int pos = atomicAdd(&cursor[d], 1);
        ssrc[pos] = ei[e];
    }
}

// ---------------- fp32 GEMM: C[M][BN] = A[M][128] @ W[128][BN] (+bias) ----------------

template <int BN, bool HAS_BIAS>
__global__ __launch_bounds__(256, 4) void k_gemm(const float* __restrict__ A,
                                                 const float* __restrict__ W,
                                                 const float* __restrict__ bias,
                                                 float* __restrict__ C, int M) {
    constexpr int BM = 128, BK = 32, CT = BN / 16;
    static_assert(CT % 4 == 0, "CT must be multiple of 4");
    __shared__ float xs[BK][BM + 4];   // k-major A tile (+4 keeps 16B alignment)
    __shared__ float ws[BK][BN];       // k-major W tile

    int tid = threadIdx.x;
    int tx = tid & 15;        // col group: cols [tx*CT, tx*CT+CT)
    int ty = tid >> 4;        // row group: rows [ty*8, ty*8+8)
    int row0 = blockIdx.x * BM;

    float acc[8][CT];
    #pragma unroll
    for (int r = 0; r < 8; r++)
        #pragma unroll
        for (int c = 0; c < CT; c++) acc[r][c] = 0.f;

    for (int k0 = 0; k0 < 128; k0 += BK) {
        // stage A (transpose to k-major)
        #pragma unroll
        for (int li = tid; li < BM * BK / 4; li += 256) {
            int r = li >> 3, c4 = li & 7;
            int grow = row0 + r;
            if (grow >= M) grow = M - 1;
            float4 v = *(const float4*)(A + (size_t)grow * 128 + k0 + c4 * 4);
            xs[c4 * 4 + 0][r] = v.x;
            xs[c4 * 4 + 1][r] = v.y;
            xs[c4 * 4 + 2][r] = v.z;
            xs[c4 * 4 + 3][r] = v.w;
        }
        // stage W (already k-major)
        #pragma unroll
        for (int li = tid; li < BK * BN / 4; li += 256) {
            int k = li / (BN / 4), c4 = li % (BN / 4);
            *(float4*)&ws[k][c4 * 4] = *(const float4*)(W + (size_t)(k0 + k) * BN + c4 * 4);
        }
        __syncthreads();

        #pragma unroll 8
        for (int kk = 0; kk < BK; kk++) {
            float a[8], b[CT];
            *(float4*)&a[0] = *(const float4*)&xs[kk][ty * 8];
            *(float4*)&a[4] = *(const float4*)&xs[kk][ty * 8 + 4];
            #pragma unroll
            for (int g = 0; g < CT / 4; g++)
                *(float4*)&b[g * 4] = *(const float4*)&ws[kk][tx * CT + g * 4];
            #pragma unroll
            for (int r = 0; r < 8; r++)
                #pragma unroll
                for (int c = 0; c < CT; c++)
                    acc[r][c] = fmaf(a[r], b[c], acc[r][c]);
        }
        __syncthreads();
    }

    float bv[CT];
    if (HAS_BIAS) {
        #pragma unroll
        for (int c = 0; c < CT; c++) bv[c] = bias[tx * CT + c];
    }
    #pragma unroll
    for (int r = 0; r < 8; r++) {
        int row = row0 + ty * 8 + r;
        if (row < M) {
            float o[CT];
            #pragma unroll
            for (int c = 0; c < CT; c++) o[c] = HAS_BIAS ? acc[r][c] + bv[c] : acc[r][c];
            #pragma unroll
            for (int g = 0; g < CT / 4; g++)
                *(float4*)(C + (size_t)row * BN + tx * CT + g * 4) = *(float4*)&o[g * 4];
        }
    }
}

// ---------------- aggregation: h2[n] = relu(b1 + dinv[n]*(sum_s h[s]*dinv[s]) + h[n]*dinv[n]^2) ----

__global__ __launch_bounds__(256) void k_agg(const float* __restrict__ h,
                                             const int* __restrict__ offs,
                                             const int* __restrict__ ssrc,
                                             const float* __restrict__ dinv,
                                             const float* __restrict__ b1,
                                             float* __restrict__ h2) {
    int wave = threadIdx.x >> 6;
    int lane = threadIdx.x & 63;
    int n = blockIdx.x * 4 + wave;
    if (n >= N_NODES) return;

    const float2* hp = (const float2*)h;
    int e0 = offs[n], e1 = offs[n + 1];
    float dn = dinv[n];

    float2 a0 = make_float2(0.f, 0.f), a1 = make_float2(0.f, 0.f);
    int j = e0;
    for (; j + 2 <= e1; j += 2) {
        int s0 = ssrc[j], s1 = ssrc[j + 1];
        float w0 = dinv[s0], w1 = dinv[s1];
        float2 v0 = hp[s0 * 64 + lane];
        float2 v1 = hp[s1 * 64 + lane];
        a0.x = fmaf(v0.x, w0, a0.x); a0.y = fmaf(v0.y, w0, a0.y);
        a1.x = fmaf(v1.x, w1, a1.x); a1.y = fmaf(v1.y, w1, a1.y);
    }
    if (j < e1) {
        int s = ssrc[j];
        float w = dinv[s];
        float2 v = hp[s * 64 + lane];
        a0.x = fmaf(v.x, w, a0.x); a0.y = fmaf(v.y, w, a0.y);
    }
    float2 vs = hp[n * 64 + lane];
    float rx = (a0.x + a1.x) * dn + vs.x * dn * dn;
    float ry = (a0.y + a1.y) * dn + vs.y * dn * dn;
    float2 bb = ((const float2*)b1)[lane];
    rx += bb.x; ry += bb.y;
    rx = rx > 0.f ? rx : 0.f;
    ry = ry > 0.f ? ry : 0.f;
    ((float2*)h2)[n * 64 + lane] = make_float2(rx, ry);
}

// ---------------- launch ----------------

extern "C" void kernel_launch(void* const* d_in, const int* in_sizes, int n_in,
                              void* d_out, int out_size, void* d_ws, size_t ws_size,
                              hipStream_t stream) {
    const float* x  = (const float*)d_in[0];
    const float* W1 = (const float*)d_in[1];
    const float* b1 = (const float*)d_in[2];
    const float* W2 = (const float*)d_in[3];
    const float* b2 = (const float*)d_in[4];
    const int*   ei = (const int*)d_in[5];
    float* out = (float*)d_out;

    char* w = (char*)d_ws;
    size_t off = 0;
    auto alloc = [&](size_t bytes) -> void* {
        void* p = w + off;
        off += (bytes + 255) & ~(size_t)255;
        return p;
    };
    float* h      = (float*)alloc((size_t)N_NODES * HIDDEN * 4);
    float* h2     = (float*)alloc((size_t)N_NODES * HIDDEN * 4);
    float* dinv   = (float*)alloc((size_t)N_NODES * 4);
    int*   cnt    = (int*)alloc((size_t)N_NODES * 4);
    int*   offs   = (int*)alloc((size_t)(N_NODES + 1) * 4);
    int*   cursor = (int*)alloc((size_t)N_NODES * 4);
    int*   ssrc   = (int*)alloc((size_t)N_EDGES * 4);
    int*   parts  = (int*)alloc((size_t)SCAN_NB * 4);

    k_init<<<(N_NODES + 255) / 256, 256, 0, stream>>>(cnt);
    k_hist<<<(N_EDGES + 255) / 256, 256, 0, stream>>>(ei, cnt);
    k_scanA<<<SCAN_NB, SCAN_BLOCK, 0, stream>>>(cnt, parts);
    k_scanB<<<1, 64, 0, stream>>>(parts, offs);
    k_scanC<<<SCAN_NB, SCAN_BLOCK, 0, stream>>>(cnt, parts, offs, cursor, dinv);
    k_bucket<<<(N_EDGES + 255) / 256, 256, 0, stream>>>(ei, cursor, ssrc);

    k_gemm<HIDDEN, false><<<(N_NODES + 127) / 128, 256, 0, stream>>>(x, W1, nullptr, h, N_NODES);
    k_agg<<<(N_NODES + 3) / 4, 256, 0, stream>>>(h, offs, ssrc, dinv, b1, h2);
    k_gemm<OUT_DIM, true><<<(N_NODES + 127) / 128, 256, 0, stream>>>(h2, W2, b2, out, N_NODES);
}

// Round 2
// 396.210 us; speedup vs baseline: 1.2890x; 1.2890x over previous
//
#include <hip/hip_runtime.h>

#define N_NODES 100000
#define N_EDGES 1600000
#define IN_DIM  128
#define HIDDEN  128
#define OUT_DIM 64

#define SCAN_BLOCK 256
#define SCAN_ITEMS 4
#define SCAN_CHUNK (SCAN_BLOCK * SCAN_ITEMS)          // 1024
#define SCAN_NB ((N_NODES + SCAN_CHUNK - 1) / SCAN_CHUNK)  // 98

typedef __attribute__((ext_vector_type(8))) short bf8_t;   // 8 x bf16 (4 VGPRs)
typedef __attribute__((ext_vector_type(4))) float f4_t;    // MFMA accumulator

__device__ __forceinline__ ushort f2b(float f) {           // fp32 -> bf16 RNE
    unsigned int u = __float_as_uint(f);
    u += 0x7fffu + ((u >> 16) & 1u);
    return (ushort)(u >> 16);
}
__device__ __forceinline__ float b2f_lo(unsigned int u) { return __uint_as_float(u << 16); }
__device__ __forceinline__ float b2f_hi(unsigned int u) { return __uint_as_float(u & 0xffff0000u); }

// ---------------- preprocessing: degree histogram + CSR by dst ----------------

__global__ void k_init(int* __restrict__ cnt) {
    int i = blockIdx.x * 256 + threadIdx.x;
    if (i < N_NODES) cnt[i] = 0;
}

__global__ void k_hist(const int* __restrict__ ei, int* __restrict__ cnt) {
    int e = blockIdx.x * 256 + threadIdx.x;
    if (e < N_EDGES) atomicAdd(&cnt[ei[N_EDGES + e]], 1);
}

__global__ void k_scanA(const int* __restrict__ cnt, int* __restrict__ partials) {
    __shared__ int sd[SCAN_BLOCK];
    int b = blockIdx.x;
    int i0 = b * SCAN_CHUNK + threadIdx.x * SCAN_ITEMS;
    int s = 0;
    #pragma unroll
    for (int j = 0; j < SCAN_ITEMS; j++) {
        int i = i0 + j;
        if (i < N_NODES) s += cnt[i];
    }
    sd[threadIdx.x] = s;
    __syncthreads();
    for (int off = SCAN_BLOCK / 2; off > 0; off >>= 1) {
        if (threadIdx.x < off) sd[threadIdx.x] += sd[threadIdx.x + off];
        __syncthreads();
    }
    if (threadIdx.x == 0) partials[b] = sd[0];
}

__global__ void k_scanB(int* __restrict__ partials, int* __restrict__ offs) {
    if (threadIdx.x == 0 && blockIdx.x == 0) {
        int run = 0;
        for (int b = 0; b < SCAN_NB; b++) {
            int t = partials[b];
            partials[b] = run;
            run += t;
        }
        offs[N_NODES] = run;       // == N_EDGES
    }
}

__global__ void k_scanC(const int* __restrict__ cnt, const int* __restrict__ partials,
                        int* __restrict__ offs, int* __restrict__ cursor,
                        float* __restrict__ dinv) {
    __shared__ int sd[SCAN_BLOCK];
    int b = blockIdx.x;
    int i0 = b * SCAN_CHUNK + threadIdx.x * SCAN_ITEMS;
    int v[SCAN_ITEMS];
    int s = 0;
    #pragma unroll
    for (int j = 0; j < SCAN_ITEMS; j++) {
        int i = i0 + j;
        v[j] = (i < N_NODES) ? cnt[i] : 0;
        s += v[j];
    }
    sd[threadIdx.x] = s;
    __syncthreads();
    for (int off = 1; off < SCAN_BLOCK; off <<= 1) {
        int t = 0;
        if ((int)threadIdx.x >= off) t = sd[threadIdx.x - off];
        __syncthreads();
        sd[threadIdx.x] += t;
        __syncthreads();
    }
    int run = partials[b] + sd[threadIdx.x] - s;
    #pragma unroll
    for (int j = 0; j < SCAN_ITEMS; j++) {
        int i = i0 + j;
        if (i < N_NODES) {
            offs[i]   = run;
            cursor[i] = run;
            dinv[i]   = rsqrtf((float)(v[j] + 1));  // +1: self-loop
            run += v[j];
        }
    }
}

__global__ void k_bucket(const int* __restrict__ ei, int* __restrict__ cursor,
                         int* __restrict__ ssrc) {
    int e = blockIdx.x * 256 + threadIdx.x;
    if (e < N_EDGES) {
        int d = ei[N_EDGES + e];
        int pos = atomicAdd(&cursor[d], 1);
        ssrc[pos] = ei[e];
    }
}

// ---------------- bf16 MFMA GEMM: C[M][BN] = A[M][128] @ W[128][BN] ----------------
// A_BF16: A is bf16 (ushort) else fp32 (converted in staging).
// OUT_BF16: store bf16 scaled by dinv[row]; else fp32 + bias.

template <int BN, bool A_BF16, bool OUT_BF16>
__global__ __launch_bounds__(256, 2) void k_mfma(const void* __restrict__ Av,
                                                 const float* __restrict__ W,
                                                 const float* __restrict__ bias,
                                                 const float* __restrict__ dinv,
                                                 void* __restrict__ Cv, int M) {
    constexpr int BM = 128, KK = 128, PAD = 8;
    constexpr int MF = (BN == 128) ? 4 : 2;
    constexpr int NF = 4;
    __shared__ ushort As[BM][KK + PAD];   // row-major bf16, 272B stride
    __shared__ ushort Bs[BN][KK + PAD];   // n-major (B transposed)

    int tid = threadIdx.x;
    int row0 = blockIdx.x * BM;

    if (A_BF16) {
        const ushort* A = (const ushort*)Av;
        #pragma unroll
        for (int i = 0; i < 8; i++) {
            int li = tid + i * 256;          // 128*16 uint4 loads
            int r = li >> 4, c8 = li & 15;
            int grow = row0 + r; if (grow > M - 1) grow = M - 1;
            uint4 v = *(const uint4*)(A + (size_t)grow * KK + c8 * 8);
            *(uint4*)&As[r][c8 * 8] = v;
        }
    } else {
        const float* A = (const float*)Av;
        #pragma unroll
        for (int i = 0; i < 16; i++) {
            int li = tid + i * 256;          // 128*32 float4 loads
            int r = li >> 5, c4 = li & 31;
            int grow = row0 + r; if (grow > M - 1) grow = M - 1;
            float4 v = *(const float4*)(A + (size_t)grow * KK + c4 * 4);
            ushort4 o;
            o.x = f2b(v.x); o.y = f2b(v.y); o.z = f2b(v.z); o.w = f2b(v.w);
            *(ushort4*)&As[r][c4 * 4] = o;
        }
    }
    #pragma unroll
    for (int i = 0; i < (KK * BN / 4) / 256; i++) {
        int li = tid + i * 256;
        int k = li / (BN / 4), n4 = li % (BN / 4);
        float4 v = *(const float4*)(W + (size_t)k * BN + n4 * 4);
        Bs[n4 * 4 + 0][k] = f2b(v.x);
        Bs[n4 * 4 + 1][k] = f2b(v.y);
        Bs[n4 * 4 + 2][k] = f2b(v.z);
        Bs[n4 * 4 + 3][k] = f2b(v.w);
    }
    __syncthreads();

    int wave = tid >> 6, lane = tid & 63;
    int lr = lane & 15, lq = lane >> 4;
    int wm0 = (BN == 128) ? (wave & 1) * 64 : wave * 32;   // wave tile origin (rows)
    int wn0 = (BN == 128) ? (wave >> 1) * 64 : 0;          // wave tile origin (cols)

    f4_t acc[MF][NF];
    #pragma unroll
    for (int mi = 0; mi < MF; mi++)
        #pragma unroll
        for (int ni = 0; ni < NF; ni++) acc[mi][ni] = (f4_t){0.f, 0.f, 0.f, 0.f};

    #pragma unroll
    for (int kb = 0; kb < 4; kb++) {
        bf8_t af[MF], bfr[NF];
        #pragma unroll
        for (int mi = 0; mi < MF; mi++)
            af[mi] = *(const bf8_t*)&As[wm0 + mi * 16 + lr][kb * 32 + lq * 8];
        #pragma unroll
        for (int ni = 0; ni < NF; ni++)
            bfr[ni] = *(const bf8_t*)&Bs[wn0 + ni * 16 + lr][kb * 32 + lq * 8];
        #pragma unroll
        for (int mi = 0; mi < MF; mi++)
            #pragma unroll
            for (int ni = 0; ni < NF; ni++)
                acc[mi][ni] = __builtin_amdgcn_mfma_f32_16x16x32_bf16(
                    af[mi], bfr[ni], acc[mi][ni], 0, 0, 0);
    }

    #pragma unroll
    for (int mi = 0; mi < MF; mi++) {
        #pragma unroll
        for (int r = 0; r < 4; r++) {
            int row = row0 + wm0 + mi * 16 + lq * 4 + r;
            if (row < M) {
                if (OUT_BF16) {
                    float dv = dinv[row];
                    ushort* C = (ushort*)Cv;
                    #pragma unroll
                    for (int ni = 0; ni < NF; ni++)
                        C[(size_t)row * BN + wn0 + ni * 16 + lr] = f2b(acc[mi][ni][r] * dv);
                } else {
                    float* C = (float*)Cv;
                    #pragma unroll
                    for (int ni = 0; ni < NF; ni++) {
                        int col = wn0 + ni * 16 + lr;
                        C[(size_t)row * BN + col] = acc[mi][ni][r] + bias[col];
                    }
                }
            }
        }
    }
}

// -------- aggregation: h2[n] = bf16(relu(b1 + dinv[n]*(hs[n] + sum_s hs[s]))) --------
// hs rows are already scaled by dinv[src] (GEMM1 epilogue), stored bf16.

__global__ __launch_bounds__(256) void k_agg(const ushort* __restrict__ h,
                                             const int* __restrict__ offs,
                                             const int* __restrict__ ssrc,
                                             const float* __restrict__ dinv,
                                             const float* __restrict__ b1,
                                             ushort* __restrict__ h2) {
    int wave = threadIdx.x >> 6;
    int lane = threadIdx.x & 63;
    int n = blockIdx.x * 4 + wave;
    if (n >= N_NODES) return;

    const unsigned int* hp = (const unsigned int*)h;  // 2 bf16 per uint, 64 uints/row
    int e0 = offs[n], e1 = offs[n + 1];

    float ax0 = 0.f, ay0 = 0.f, ax1 = 0.f, ay1 = 0.f;
    float ax2 = 0.f, ay2 = 0.f, ax3 = 0.f, ay3 = 0.f;
    int j = e0;
    for (; j + 4 <= e1; j += 4) {
        int s0 = ssrc[j], s1 = ssrc[j + 1], s2 = ssrc[j + 2], s3 = ssrc[j + 3];
        unsigned int u0 = hp[s0 * 64 + lane];
        unsigned int u1 = hp[s1 * 64 + lane];
        unsigned int u2 = hp[s2 * 64 + lane];
        unsigned int u3 = hp[s3 * 64 + lane];
        ax0 += b2f_lo(u0); ay0 += b2f_hi(u0);
        ax1 += b2f_lo(u1); ay1 += b2f_hi(u1);
        ax2 += b2f_lo(u2); ay2 += b2f_hi(u2);
        ax3 += b2f_lo(u3); ay3 += b2f_hi(u3);
    }
    for (; j < e1; j++) {
        int s = ssrc[j];
        unsigned int u = hp[s * 64 + lane];
        ax0 += b2f_lo(u); ay0 += b2f_hi(u);
    }
    unsigned int us = hp[n * 64 + lane];          // self term: hs[n]*dinv[n]
    float dn = dinv[n];
    float rx = (ax0 + ax1 + ax2 + ax3 + b2f_lo(us)) * dn;
    float ry = (ay0 + ay1 + ay2 + ay3 + b2f_hi(us)) * dn;
    float2 bb = ((const float2*)b1)[lane];
    rx += bb.x; ry += bb.y;
    rx = rx > 0.f ? rx : 0.f;
    ry = ry > 0.f ? ry : 0.f;
    unsigned int o = ((unsigned int)f2b(ry) << 16) | (unsigned int)f2b(rx);
    ((unsigned int*)h2)[n * 64 + lane] = o;
}

// ---------------- launch ----------------

extern "C" void kernel_launch(void* const* d_in, const int* in_sizes, int n_in,
                              void* d_out, int out_size, void* d_ws, size_t ws_size,
                              hipStream_t stream) {
    const float* x  = (const float*)d_in[0];
    const float* W1 = (const float*)d_in[1];
    const float* b1 = (const float*)d_in[2];
    const float* W2 = (const float*)d_in[3];
    const float* b2 = (const float*)d_in[4];
    const int*   ei = (const int*)d_in[5];
    float* out = (float*)d_out;

    char* w = (char*)d_ws;
    size_t off = 0;
    auto alloc = [&](size_t bytes) -> void* {
        void* p = w + off;
        off += (bytes + 255) & ~(size_t)255;
        return p;
    };
    ushort* h     = (ushort*)alloc((size_t)N_NODES * HIDDEN * 2);   // bf16, dinv-scaled
    ushort* h2    = (ushort*)alloc((size_t)N_NODES * HIDDEN * 2);   // bf16
    float* dinv   = (float*)alloc((size_t)N_NODES * 4);
    int*   cnt    = (int*)alloc((size_t)N_NODES * 4);
    int*   offs   = (int*)alloc((size_t)(N_NODES + 1) * 4);
    int*   cursor = (int*)alloc((size_t)N_NODES * 4);
    int*   ssrc   = (int*)alloc((size_t)N_EDGES * 4);
    int*   parts  = (int*)alloc((size_t)SCAN_NB * 4);

    k_init<<<(N_NODES + 255) / 256, 256, 0, stream>>>(cnt);
    k_hist<<<(N_EDGES + 255) / 256, 256, 0, stream>>>(ei, cnt);
    k_scanA<<<SCAN_NB, SCAN_BLOCK, 0, stream>>>(cnt, parts);
    k_scanB<<<1, 64, 0, stream>>>(parts, offs);
    k_scanC<<<SCAN_NB, SCAN_BLOCK, 0, stream>>>(cnt, parts, offs, cursor, dinv);
    k_bucket<<<(N_EDGES + 255) / 256, 256, 0, stream>>>(ei, cursor, ssrc);

    k_mfma<HIDDEN, false, true><<<(N_NODES + 127) / 128, 256, 0, stream>>>(
        x, W1, nullptr, dinv, h, N_NODES);
    k_agg<<<(N_NODES + 3) / 4, 256, 0, stream>>>(h, offs, ssrc, dinv, b1, h2);
    k_mfma<OUT_DIM, true, false><<<(N_NODES + 127) / 128, 256, 0, stream>>>(
        h2, W2, b2, nullptr, out, N_NODES);
}

// Round 3
// 258.774 us; speedup vs baseline: 1.9737x; 1.5311x over previous
//
#include <hip/hip_runtime.h>

#define N_NODES 100000
#define N_EDGES 1600000
#define IN_DIM  128
#define HIDDEN  128
#define OUT_DIM 64

#define NB_COARSE ((N_NODES + 255) / 256)            // 391 coarse buckets (256 nodes each)
#define EPB 4096                                     // edges per block (partition passes)
#define NBLK_E ((N_EDGES + EPB - 1) / EPB)           // 391 blocks
#define CSR_CAP 5376                                 // LDS staging capacity (21 KB)

typedef __attribute__((ext_vector_type(8))) short bf8_t;   // 8 x bf16 (4 VGPRs)
typedef __attribute__((ext_vector_type(4))) float f4_t;    // MFMA accumulator

__device__ __forceinline__ ushort f2b(float f) {           // fp32 -> bf16 RNE
    unsigned int u = __float_as_uint(f);
    u += 0x7fffu + ((u >> 16) & 1u);
    return (ushort)(u >> 16);
}
__device__ __forceinline__ float b2f_lo(unsigned int u) { return __uint_as_float(u << 16); }
__device__ __forceinline__ float b2f_hi(unsigned int u) { return __uint_as_float(u & 0xffff0000u); }

// ---------------- two-level counting-sort CSR build ----------------

__global__ void k_zero(int* __restrict__ coarseCnt) {
    int t = threadIdx.x;
    if (t < NB_COARSE) coarseCnt[t] = 0;
}

__global__ __launch_bounds__(256) void k_chist(const int* __restrict__ ei,
                                               int* __restrict__ coarseCnt) {
    __shared__ int lh[NB_COARSE];
    int t = threadIdx.x;
    for (int i = t; i < NB_COARSE; i += 256) lh[i] = 0;
    __syncthreads();
    int e0 = blockIdx.x * EPB;
    #pragma unroll
    for (int j = 0; j < EPB / 256; j++) {
        int e = e0 + j * 256 + t;
        if (e < N_EDGES) atomicAdd(&lh[ei[N_EDGES + e] >> 8], 1);
    }
    __syncthreads();
    for (int i = t; i < NB_COARSE; i += 256)
        if (lh[i] > 0) atomicAdd(&coarseCnt[i], lh[i]);
}

__global__ void k_cscan(const int* __restrict__ coarseCnt, int* __restrict__ base,
                        int* __restrict__ cursor, int* __restrict__ offs) {
    __shared__ int sa[512], sb[512];
    int t = threadIdx.x;
    int v = (t < NB_COARSE) ? coarseCnt[t] : 0;
    sa[t] = v;
    __syncthreads();
    int* s = sa; int* d = sb;
    for (int off = 1; off < 512; off <<= 1) {
        int x = s[t];
        if (t >= off) x += s[t - off];
        d[t] = x;
        __syncthreads();
        int* tmp = s; s = d; d = tmp;
    }
    if (t < NB_COARSE) {
        int excl = s[t] - v;
        base[t]   = excl;
        cursor[t] = excl;
    }
    if (t == 0) {
        base[NB_COARSE] = N_EDGES;
        offs[N_NODES]   = N_EDGES;
    }
}

__global__ __launch_bounds__(256) void k_part(const int* __restrict__ ei,
                                              int* __restrict__ cursor,
                                              unsigned int* __restrict__ part) {
    __shared__ int lh[NB_COARSE];     // local hist, then local cursor
    __shared__ int lbase[NB_COARSE];  // global base of this block's run per bucket
    int t = threadIdx.x;
    for (int i = t; i < NB_COARSE; i += 256) lh[i] = 0;
    __syncthreads();
    int e0 = blockIdx.x * EPB;
    int srcv[EPB / 256], dstv[EPB / 256];
    #pragma unroll
    for (int j = 0; j < EPB / 256; j++) {
        int e = e0 + j * 256 + t;
        if (e < N_EDGES) {
            srcv[j] = ei[e];
            dstv[j] = ei[N_EDGES + e];
            atomicAdd(&lh[dstv[j] >> 8], 1);
        } else dstv[j] = -1;
    }
    __syncthreads();
    for (int i = t; i < NB_COARSE; i += 256) {
        int c = lh[i];
        lbase[i] = (c > 0) ? atomicAdd(&cursor[i], c) : 0;
        lh[i] = 0;                    // becomes local cursor
    }
    __syncthreads();
    #pragma unroll
    for (int j = 0; j < EPB / 256; j++) {
        if (dstv[j] >= 0) {
            int b = dstv[j] >> 8;
            int pos = lbase[b] + atomicAdd(&lh[b], 1);
            part[pos] = ((unsigned int)(dstv[j] & 255) << 24) | (unsigned int)srcv[j];
        }
    }
}

__global__ __launch_bounds__(256) void k_csr(const unsigned int* __restrict__ part,
                                             const int* __restrict__ base,
                                             int* __restrict__ offs,
                                             float* __restrict__ dinv,
                                             int* __restrict__ ssrc) {
    __shared__ int lh[256];           // per-node degree, then per-node cursor
    __shared__ int lsc[256];          // scan scratch
    __shared__ unsigned int stage[CSR_CAP];
    int t = threadIdx.x;
    int b = blockIdx.x;
    int rbeg = base[b], rend = base[b + 1];
    int cnt = rend - rbeg;
    int node0 = b << 8;
    int nloc = min(256, N_NODES - node0);
    bool fits = (cnt <= CSR_CAP);
    lh[t] = 0;
    __syncthreads();
    for (int i = t; i < cnt; i += 256) {
        unsigned int u = part[rbeg + i];
        if (fits) stage[i] = u;
        atomicAdd(&lh[u >> 24], 1);
    }
    __syncthreads();
    int v = lh[t];
    lsc[t] = v;
    __syncthreads();
    for (int off = 1; off < 256; off <<= 1) {
        int add = (t >= off) ? lsc[t - off] : 0;
        __syncthreads();
        lsc[t] += add;
        __syncthreads();
    }
    int ep = lsc[t] - v;              // exclusive prefix
    if (t < nloc) {
        offs[node0 + t] = rbeg + ep;
        dinv[node0 + t] = rsqrtf((float)(v + 1));   // +1: self-loop
    }
    lh[t] = ep;                       // per-node running cursor
    __syncthreads();
    for (int i = t; i < cnt; i += 256) {
        unsigned int u = fits ? stage[i] : part[rbeg + i];
        int d = u >> 24;
        int pos = atomicAdd(&lh[d], 1);
        ssrc[rbeg + pos] = (int)(u & 0xFFFFFFu);
    }
}

// ---------------- bf16 MFMA GEMM: C[M][BN] = A[M][128] @ W[128][BN] ----------------

template <int BN, bool A_BF16, bool OUT_BF16>
__global__ __launch_bounds__(256, 2) void k_mfma(const void* __restrict__ Av,
                                                 const float* __restrict__ W,
                                                 const float* __restrict__ bias,
                                                 const float* __restrict__ dinv,
                                                 void* __restrict__ Cv, int M) {
    constexpr int BM = 128, KK = 128, PAD = 8;
    constexpr int MF = (BN == 128) ? 4 : 2;
    constexpr int NF = 4;
    __shared__ ushort As[BM][KK + PAD];
    __shared__ ushort Bs[BN][KK + PAD];

    int tid = threadIdx.x;
    int row0 = blockIdx.x * BM;

    if (A_BF16) {
        const ushort* A = (const ushort*)Av;
        #pragma unroll
        for (int i = 0; i < 8; i++) {
            int li = tid + i * 256;
            int r = li >> 4, c8 = li & 15;
            int grow = row0 + r; if (grow > M - 1) grow = M - 1;
            uint4 v = *(const uint4*)(A + (size_t)grow * KK + c8 * 8);
            *(uint4*)&As[r][c8 * 8] = v;
        }
    } else {
        const float* A = (const float*)Av;
        #pragma unroll
        for (int i = 0; i < 16; i++) {
            int li = tid + i * 256;
            int r = li >> 5, c4 = li & 31;
            int grow = row0 + r; if (grow > M - 1) grow = M - 1;
            float4 v = *(const float4*)(A + (size_t)grow * KK + c4 * 4);
            ushort4 o;
            o.x = f2b(v.x); o.y = f2b(v.y); o.z = f2b(v.z); o.w = f2b(v.w);
            *(ushort4*)&As[r][c4 * 4] = o;
        }
    }
    #pragma unroll
    for (int i = 0; i < (KK * BN / 4) / 256; i++) {
        int li = tid + i * 256;
        int k = li / (BN / 4), n4 = li % (BN / 4);
        float4 v = *(const float4*)(W + (size_t)k * BN + n4 * 4);
        Bs[n4 * 4 + 0][k] = f2b(v.x);
        Bs[n4 * 4 + 1][k] = f2b(v.y);
        Bs[n4 * 4 + 2][k] = f2b(v.z);
        Bs[n4 * 4 + 3][k] = f2b(v.w);
    }
    __syncthreads();

    int wave = tid >> 6, lane = tid & 63;
    int lr = lane & 15, lq = lane >> 4;
    int wm0 = (BN == 128) ? (wave & 1) * 64 : wave * 32;
    int wn0 = (BN == 128) ? (wave >> 1) * 64 : 0;

    f4_t acc[MF][NF];
    #pragma unroll
    for (int mi = 0; mi < MF; mi++)
        #pragma unroll
        for (int ni = 0; ni < NF; ni++) acc[mi][ni] = (f4_t){0.f, 0.f, 0.f, 0.f};

    #pragma unroll
    for (int kb = 0; kb < 4; kb++) {
        bf8_t af[MF], bfr[NF];
        #pragma unroll
        for (int mi = 0; mi < MF; mi++)
            af[mi] = *(const bf8_t*)&As[wm0 + mi * 16 + lr][kb * 32 + lq * 8];
        #pragma unroll
        for (int ni = 0; ni < NF; ni++)
            bfr[ni] = *(const bf8_t*)&Bs[wn0 + ni * 16 + lr][kb * 32 + lq * 8];
        #pragma unroll
        for (int mi = 0; mi < MF; mi++)
            #pragma unroll
            for (int ni = 0; ni < NF; ni++)
                acc[mi][ni] = __builtin_amdgcn_mfma_f32_16x16x32_bf16(
                    af[mi], bfr[ni], acc[mi][ni], 0, 0, 0);
    }

    #pragma unroll
    for (int mi = 0; mi < MF; mi++) {
        #pragma unroll
        for (int r = 0; r < 4; r++) {
            int row = row0 + wm0 + mi * 16 + lq * 4 + r;
            if (row < M) {
                if (OUT_BF16) {
                    float dv = dinv[row];
                    ushort* C = (ushort*)Cv;
                    #pragma unroll
                    for (int ni = 0; ni < NF; ni++)
                        C[(size_t)row * BN + wn0 + ni * 16 + lr] = f2b(acc[mi][ni][r] * dv);
                } else {
                    float* C = (float*)Cv;
                    #pragma unroll
                    for (int ni = 0; ni < NF; ni++) {
                        int col = wn0 + ni * 16 + lr;
                        C[(size_t)row * BN + col] = acc[mi][ni][r] + bias[col];
                    }
                }
            }
        }
    }
}

// -------- aggregation: h2[n] = bf16(relu(b1 + dinv[n]*(hs[n] + sum_s hs[s]))) --------

__global__ __launch_bounds__(256) void k_agg(const ushort* __restrict__ h,
                                             const int* __restrict__ offs,
                                             const int* __restrict__ ssrc,
                                             const float* __restrict__ dinv,
                                             const float* __restrict__ b1,
                                             ushort* __restrict__ h2) {
    int wave = threadIdx.x >> 6;
    int lane = threadIdx.x & 63;
    int n = blockIdx.x * 4 + wave;
    if (n >= N_NODES) return;

    const unsigned int* hp = (const unsigned int*)h;
    int e0 = offs[n], e1 = offs[n + 1];

    float ax0 = 0.f, ay0 = 0.f, ax1 = 0.f, ay1 = 0.f;
    float ax2 = 0.f, ay2 = 0.f, ax3 = 0.f, ay3 = 0.f;
    int j = e0;
    for (; j + 4 <= e1; j += 4) {
        int s0 = ssrc[j], s1 = ssrc[j + 1], s2 = ssrc[j + 2], s3 = ssrc[j + 3];
        unsigned int u0 = hp[s0 * 64 + lane];
        unsigned int u1 = hp[s1 * 64 + lane];
        unsigned int u2 = hp[s2 * 64 + lane];
        unsigned int u3 = hp[s3 * 64 + lane];
        ax0 += b2f_lo(u0); ay0 += b2f_hi(u0);
        ax1 += b2f_lo(u1); ay1 += b2f_hi(u1);
        ax2 += b2f_lo(u2); ay2 += b2f_hi(u2);
        ax3 += b2f_lo(u3); ay3 += b2f_hi(u3);
    }
    for (; j < e1; j++) {
        int s = ssrc[j];
        unsigned int u = hp[s * 64 + lane];
        ax0 += b2f_lo(u); ay0 += b2f_hi(u);
    }
    unsigned int us = hp[n * 64 + lane];
    float dn = dinv[n];
    float rx = (ax0 + ax1 + ax2 + ax3 + b2f_lo(us)) * dn;
    float ry = (ay0 + ay1 + ay2 + ay3 + b2f_hi(us)) * dn;
    float2 bb = ((const float2*)b1)[lane];
    rx += bb.x; ry += bb.y;
    rx = rx > 0.f ? rx : 0.f;
    ry = ry > 0.f ? ry : 0.f;
    unsigned int o = ((unsigned int)f2b(ry) << 16) | (unsigned int)f2b(rx);
    ((unsigned int*)h2)[n * 64 + lane] = o;
}

// ---------------- launch ----------------

extern "C" void kernel_launch(void* const* d_in, const int* in_sizes, int n_in,
                              void* d_out, int out_size, void* d_ws, size_t ws_size,
                              hipStream_t stream) {
    const float* x  = (const float*)d_in[0];
    const float* W1 = (const float*)d_in[1];
    const float* b1 = (const float*)d_in[2];
    const float* W2 = (const float*)d_in[3];
    const float* b2 = (const float*)d_in[4];
    const int*   ei = (const int*)d_in[5];
    float* out = (float*)d_out;

    char* w = (char*)d_ws;
    size_t off = 0;
    auto alloc = [&](size_t bytes) -> void* {
        void* p = w + off;
        off += (bytes + 255) & ~(size_t)255;
        return p;
    };
    ushort* h      = (ushort*)alloc((size_t)N_NODES * HIDDEN * 2);   // bf16, dinv-scaled
    ushort* h2     = (ushort*)alloc((size_t)N_NODES * HIDDEN * 2);   // bf16
    float* dinv    = (float*)alloc((size_t)N_NODES * 4);
    int*   offs    = (int*)alloc((size_t)(N_NODES + 1) * 4);
    int*   ssrc    = (int*)alloc((size_t)N_EDGES * 4);
    unsigned int* part = (unsigned int*)alloc((size_t)N_EDGES * 4);
    int*   coarse  = (int*)alloc((size_t)NB_COARSE * 4);
    int*   base    = (int*)alloc((size_t)(NB_COARSE + 1) * 4);
    int*   cursor  = (int*)alloc((size_t)NB_COARSE * 4);

    k_zero<<<1, 512, 0, stream>>>(coarse);
    k_chist<<<NBLK_E, 256, 0, stream>>>(ei, coarse);
    k_cscan<<<1, 512, 0, stream>>>(coarse, base, cursor, offs);
    k_part<<<NBLK_E, 256, 0, stream>>>(ei, cursor, part);
    k_csr<<<NB_COARSE, 256, 0, stream>>>(part, base, offs, dinv, ssrc);

    k_mfma<HIDDEN, false, true><<<(N_NODES + 127) / 128, 256, 0, stream>>>(
        x, W1, nullptr, dinv, h, N_NODES);
    k_agg<<<(N_NODES + 3) / 4, 256, 0, stream>>>(h, offs, ssrc, dinv, b1, h2);
    k_mfma<OUT_DIM, true, false><<<(N_NODES + 127) / 128, 256, 0, stream>>>(
        h2, W2, b2, nullptr, out, N_NODES);
}

// Round 4
// 235.805 us; speedup vs baseline: 2.1659x; 1.0974x over previous
//
#include <hip/hip_runtime.h>

#define N_NODES 100000
#define N_EDGES 1600000
#define IN_DIM  128
#define HIDDEN  128
#define OUT_DIM 64

#define NB_COARSE ((N_NODES + 255) / 256)   // 391 coarse buckets (256 nodes each)
#define EPB 4096                            // edges per block in k_part
#define NBLK_E ((N_EDGES + EPB - 1) / EPB)  // 391 blocks
#define CAP 5120                            // fixed bucket capacity (mean 4092 + 16 sigma)
#define PCAP 6912                           // padded bucket capacity (CAP + 256*7), mult of 8

typedef __attribute__((ext_vector_type(8))) short bf8_t;   // 8 x bf16 (4 VGPRs)
typedef __attribute__((ext_vector_type(4))) float f4_t;    // MFMA accumulator

__device__ __forceinline__ ushort f2b(float f) {           // fp32 -> bf16 RNE
    unsigned int u = __float_as_uint(f);
    u += 0x7fffu + ((u >> 16) & 1u);
    return (ushort)(u >> 16);
}
__device__ __forceinline__ float b2f_lo(unsigned int u) { return __uint_as_float(u << 16); }
__device__ __forceinline__ float b2f_hi(unsigned int u) { return __uint_as_float(u & 0xffff0000u); }

// ---------------- init: bucket cursors to fixed bases; zero h sentinel row ----------------

__global__ void k_zero(int* __restrict__ cursor, unsigned int* __restrict__ hz) {
    int t = threadIdx.x;
    if (t < NB_COARSE) cursor[t] = t * CAP;
    if (t >= NB_COARSE && t < NB_COARSE + 64)
        hz[(size_t)N_NODES * 64 + (t - NB_COARSE)] = 0u;   // bf16 zero row (256 B)
}

// ---------------- single-pass bucketed partition (fixed bases, no global scan) ----------------

__global__ __launch_bounds__(256) void k_part(const int* __restrict__ ei,
                                              int* __restrict__ cursor,
                                              unsigned int* __restrict__ part) {
    __shared__ int lh[NB_COARSE];     // local hist, then local cursor
    __shared__ int lbase[NB_COARSE];  // global base of this block's run per bucket
    int t = threadIdx.x;
    for (int i = t; i < NB_COARSE; i += 256) lh[i] = 0;
    __syncthreads();
    int e0 = blockIdx.x * EPB;
    int srcv[EPB / 256], dstv[EPB / 256];
    #pragma unroll
    for (int j = 0; j < EPB / 256; j++) {
        int e = e0 + j * 256 + t;
        if (e < N_EDGES) {
            srcv[j] = ei[e];
            dstv[j] = ei[N_EDGES + e];
            atomicAdd(&lh[dstv[j] >> 8], 1);
        } else dstv[j] = -1;
    }
    __syncthreads();
    for (int i = t; i < NB_COARSE; i += 256) {
        int c = lh[i];
        lbase[i] = (c > 0) ? atomicAdd(&cursor[i], c) : 0;
        lh[i] = 0;                    // becomes local cursor
    }
    __syncthreads();
    #pragma unroll
    for (int j = 0; j < EPB / 256; j++) {
        if (dstv[j] >= 0) {
            int b = dstv[j] >> 8;
            int pos = lbase[b] + atomicAdd(&lh[b], 1);
            part[pos] = ((unsigned int)(dstv[j] & 255) << 24) | (unsigned int)srcv[j];
        }
    }
}

// ------- per-bucket CSR finalize: padded per-node ranges (pad -> sentinel N_NODES) -------

__global__ __launch_bounds__(256) void k_csr(const unsigned int* __restrict__ part,
                                             const int* __restrict__ cursor,
                                             int* __restrict__ offs,
                                             int* __restrict__ pcnt,
                                             float* __restrict__ dinv,
                                             int* __restrict__ ssrc) {
    __shared__ int ldeg[256], lsc[256], lcur[256], sob[256];
    __shared__ unsigned int stage[CAP];
    int t = threadIdx.x;
    int b = blockIdx.x;
    int rbeg = b * CAP;
    int cnt = cursor[b] - rbeg;       // edges landed in this bucket
    int node0 = b << 8;
    ldeg[t] = 0;
    __syncthreads();
    for (int i = t; i < cnt; i += 256) {
        unsigned int u = part[rbeg + i];
        stage[i] = u;
        atomicAdd(&ldeg[u >> 24], 1);
    }
    __syncthreads();
    int v = ldeg[t];
    int pv = (v + 7) & ~7;            // padded to multiple of 8
    lsc[t] = pv;
    __syncthreads();
    for (int off = 1; off < 256; off <<= 1) {
        int add = (t >= off) ? lsc[t - off] : 0;
        __syncthreads();
        lsc[t] += add;
        __syncthreads();
    }
    int ob = b * PCAP + (lsc[t] - pv);   // padded output base for node (node0+t)
    sob[t] = ob;
    lcur[t] = 0;
    if (node0 + t < N_NODES) {
        offs[node0 + t] = ob;
        pcnt[node0 + t] = pv;
        dinv[node0 + t] = rsqrtf((float)(v + 1));   // +1: self-loop
    }
    __syncthreads();
    for (int i = t; i < cnt; i += 256) {
        unsigned int u = stage[i];
        int d = u >> 24;
        int pos = atomicAdd(&lcur[d], 1);
        ssrc[sob[d] + pos] = (int)(u & 0xFFFFFFu);
    }
    for (int i = v; i < pv; i++) ssrc[ob + i] = N_NODES;   // sentinel pads (zero row)
}

// ---------------- bf16 MFMA GEMM: C[M][BN] = A[M][128] @ W[128][BN] ----------------

template <int BN, bool A_BF16, bool OUT_BF16>
__global__ __launch_bounds__(256, 2) void k_mfma(const void* __restrict__ Av,
                                                 const float* __restrict__ W,
                                                 const float* __restrict__ bias,
                                                 const float* __restrict__ dinv,
                                                 void* __restrict__ Cv, int M) {
    constexpr int BM = 128, KK = 128, PAD = 8;
    constexpr int MF = (BN == 128) ? 4 : 2;
    constexpr int NF = 4;
    __shared__ ushort As[BM][KK + PAD];
    __shared__ ushort Bs[BN][KK + PAD];

    int tid = threadIdx.x;
    int row0 = blockIdx.x * BM;

    if (A_BF16) {
        const ushort* A = (const ushort*)Av;
        #pragma unroll
        for (int i = 0; i < 8; i++) {
            int li = tid + i * 256;
            int r = li >> 4, c8 = li & 15;
            int grow = row0 + r; if (grow > M - 1) grow = M - 1;
            uint4 v = *(const uint4*)(A + (size_t)grow * KK + c8 * 8);
            *(uint4*)&As[r][c8 * 8] = v;
        }
    } else {
        const float* A = (const float*)Av;
        #pragma unroll
        for (int i = 0; i < 16; i++) {
            int li = tid + i * 256;
            int r = li >> 5, c4 = li & 31;
            int grow = row0 + r; if (grow > M - 1) grow = M - 1;
            float4 v = *(const float4*)(A + (size_t)grow * KK + c4 * 4);
            ushort4 o;
            o.x = f2b(v.x); o.y = f2b(v.y); o.z = f2b(v.z); o.w = f2b(v.w);
            *(ushort4*)&As[r][c4 * 4] = o;
        }
    }
    #pragma unroll
    for (int i = 0; i < (KK * BN / 4) / 256; i++) {
        int li = tid + i * 256;
        int k = li / (BN / 4), n4 = li % (BN / 4);
        float4 v = *(const float4*)(W + (size_t)k * BN + n4 * 4);
        Bs[n4 * 4 + 0][k] = f2b(v.x);
        Bs[n4 * 4 + 1][k] = f2b(v.y);
        Bs[n4 * 4 + 2][k] = f2b(v.z);
        Bs[n4 * 4 + 3][k] = f2b(v.w);
    }
    __syncthreads();

    int wave = tid >> 6, lane = tid & 63;
    int lr = lane & 15, lq = lane >> 4;
    int wm0 = (BN == 128) ? (wave & 1) * 64 : wave * 32;
    int wn0 = (BN == 128) ? (wave >> 1) * 64 : 0;

    f4_t acc[MF][NF];
    #pragma unroll
    for (int mi = 0; mi < MF; mi++)
        #pragma unroll
        for (int ni = 0; ni < NF; ni++) acc[mi][ni] = (f4_t){0.f, 0.f, 0.f, 0.f};

    #pragma unroll
    for (int kb = 0; kb < 4; kb++) {
        bf8_t af[MF], bfr[NF];
        #pragma unroll
        for (int mi = 0; mi < MF; mi++)
            af[mi] = *(const bf8_t*)&As[wm0 + mi * 16 + lr][kb * 32 + lq * 8];
        #pragma unroll
        for (int ni = 0; ni < NF; ni++)
            bfr[ni] = *(const bf8_t*)&Bs[wn0 + ni * 16 + lr][kb * 32 + lq * 8];
        #pragma unroll
        for (int mi = 0; mi < MF; mi++)
            #pragma unroll
            for (int ni = 0; ni < NF; ni++)
                acc[mi][ni] = __builtin_amdgcn_mfma_f32_16x16x32_bf16(
                    af[mi], bfr[ni], acc[mi][ni], 0, 0, 0);
    }

    #pragma unroll
    for (int mi = 0; mi < MF; mi++) {
        #pragma unroll
        for (int r = 0; r < 4; r++) {
            int row = row0 + wm0 + mi * 16 + lq * 4 + r;
            if (row < M) {
                if (OUT_BF16) {
                    float dv = dinv[row];
                    ushort* C = (ushort*)Cv;
                    #pragma unroll
                    for (int ni = 0; ni < NF; ni++)
                        C[(size_t)row * BN + wn0 + ni * 16 + lr] = f2b(acc[mi][ni][r] * dv);
                } else {
                    float* C = (float*)Cv;
                    #pragma unroll
                    for (int ni = 0; ni < NF; ni++) {
                        int col = wn0 + ni * 16 + lr;
                        C[(size_t)row * BN + col] = acc[mi][ni][r] + bias[col];
                    }
                }
            }
        }
    }
}

// -------- aggregation: h2[n] = bf16(relu(b1 + dinv[n]*(hs[n] + sum_s hs[s]))) --------
// Edge lists are padded to multiples of 8 with sentinel N_NODES (zero row).

__global__ __launch_bounds__(256) void k_agg(const ushort* __restrict__ h,
                                             const int* __restrict__ offs,
                                             const int* __restrict__ pcnt,
                                             const int* __restrict__ ssrc,
                                             const float* __restrict__ dinv,
                                             const float* __restrict__ b1,
                                             ushort* __restrict__ h2) {
    int wave = threadIdx.x >> 6;
    int lane = threadIdx.x & 63;
    int n = blockIdx.x * 4 + wave;
    if (n >= N_NODES) return;

    const unsigned int* hp = (const unsigned int*)h;  // 2 bf16 per uint, 64 uints/row
    int e0 = offs[n];
    int iters = pcnt[n] >> 3;
    const uint4* ip = (const uint4*)(ssrc + e0);      // 32B-aligned (e0 mult of 8)

    float ax0 = 0.f, ay0 = 0.f, ax1 = 0.f, ay1 = 0.f;
    float ax2 = 0.f, ay2 = 0.f, ax3 = 0.f, ay3 = 0.f;
    uint4 i0, i1;
    if (iters > 0) { i0 = ip[0]; i1 = ip[1]; }
    for (int it = 0; it < iters; it++) {
        uint4 nx0 = i0, nx1 = i1;
        if (it + 1 < iters) { nx0 = ip[(it + 1) * 2]; nx1 = ip[(it + 1) * 2 + 1]; }
        unsigned int u0 = hp[i0.x * 64 + lane];
        unsigned int u1 = hp[i0.y * 64 + lane];
        unsigned int u2 = hp[i0.z * 64 + lane];
        unsigned int u3 = hp[i0.w * 64 + lane];
        unsigned int u4 = hp[i1.x * 64 + lane];
        unsigned int u5 = hp[i1.y * 64 + lane];
        unsigned int u6 = hp[i1.z * 64 + lane];
        unsigned int u7 = hp[i1.w * 64 + lane];
        ax0 += b2f_lo(u0); ay0 += b2f_hi(u0);
        ax1 += b2f_lo(u1); ay1 += b2f_hi(u1);
        ax2 += b2f_lo(u2); ay2 += b2f_hi(u2);
        ax3 += b2f_lo(u3); ay3 += b2f_hi(u3);
        ax0 += b2f_lo(u4); ay0 += b2f_hi(u4);
        ax1 += b2f_lo(u5); ay1 += b2f_hi(u5);
        ax2 += b2f_lo(u6); ay2 += b2f_hi(u6);
        ax3 += b2f_lo(u7); ay3 += b2f_hi(u7);
        i0 = nx0; i1 = nx1;
    }
    unsigned int us = hp[(size_t)n * 64 + lane];      // self term: hs[n]*dinv[n]
    float dn = dinv[n];
    float rx = (ax0 + ax1 + ax2 + ax3 + b2f_lo(us)) * dn;
    float ry = (ay0 + ay1 + ay2 + ay3 + b2f_hi(us)) * dn;
    float2 bb = ((const float2*)b1)[lane];
    rx += bb.x; ry += bb.y;
    rx = rx > 0.f ? rx : 0.f;
    ry = ry > 0.f ? ry : 0.f;
    unsigned int o = ((unsigned int)f2b(ry) << 16) | (unsigned int)f2b(rx);
    ((unsigned int*)h2)[(size_t)n * 64 + lane] = o;
}

// ---------------- launch ----------------

extern "C" void kernel_launch(void* const* d_in, const int* in_sizes, int n_in,
                              void* d_out, int out_size, void* d_ws, size_t ws_size,
                              hipStream_t stream) {
    const float* x  = (const float*)d_in[0];
    const float* W1 = (const float*)d_in[1];
    const float* b1 = (const float*)d_in[2];
    const float* W2 = (const float*)d_in[3];
    const float* b2 = (const float*)d_in[4];
    const int*   ei = (const int*)d_in[5];
    float* out = (float*)d_out;

    char* w = (char*)d_ws;
    size_t off = 0;
    auto alloc = [&](size_t bytes) -> void* {
        void* p = w + off;
        off += (bytes + 255) & ~(size_t)255;
        return p;
    };
    ushort* h      = (ushort*)alloc((size_t)(N_NODES + 1) * HIDDEN * 2);  // +1 sentinel row
    ushort* h2     = (ushort*)alloc((size_t)N_NODES * HIDDEN * 2);
    float* dinv    = (float*)alloc((size_t)N_NODES * 4);
    int*   offs    = (int*)alloc((size_t)N_NODES * 4);
    int*   pcnt    = (int*)alloc((size_t)N_NODES * 4);
    int*   ssrc    = (int*)alloc((size_t)NB_COARSE * PCAP * 4);
    unsigned int* part = (unsigned int*)alloc((size_t)NB_COARSE * CAP * 4);
    int*   cursor  = (int*)alloc((size_t)NB_COARSE * 4);

    k_zero<<<1, 512, 0, stream>>>(cursor, (unsigned int*)h);
    k_part<<<NBLK_E, 256, 0, stream>>>(ei, cursor, part);
    k_csr<<<NB_COARSE, 256, 0, stream>>>(part, cursor, offs, pcnt, dinv, ssrc);

    k_mfma<HIDDEN, false, true><<<(N_NODES + 127) / 128, 256, 0, stream>>>(
        x, W1, nullptr, dinv, h, N_NODES);
    k_agg<<<(N_NODES + 3) / 4, 256, 0, stream>>>(h, offs, pcnt, ssrc, dinv, b1, h2);
    k_mfma<OUT_DIM, true, false><<<(N_NODES + 127) / 128, 256, 0, stream>>>(
        h2, W2, b2, nullptr, out, N_NODES);
}